// Round 3
// baseline (221.377 us; speedup 1.0000x reference)
//
#include <hip/hip_runtime.h>

#define NN 500
#define SLOPEC 0.01f
#define NBLK 768          // 3 blocks/CU; capacity is 4/CU (VGPR<=128 via launch_bounds,
                          // LDS 6144B, 256 thr) -> 1024 slots >= 768 with 25% slack:
                          // all blocks co-resident unconditionally -> barrier safe.
#define NLEAF 32          // two-level barrier: 32 leaves x 24 blocks

typedef unsigned short us;
typedef unsigned int u32;
typedef unsigned long long u64;

// ---- canonical fp32 copies of all inputs + scratch, as device globals ----
// (16B-aligned by construction: safe for float4 loads. Harness input buffers
//  are NOT guaranteed 16B-aligned — inputs only ever read with scalar loads.)
__device__ __align__(16) float g_imf[16000];
__device__ __align__(16) float g_c[1504];
__device__ __align__(16) float g_ct[1504];
__device__ __align__(16) float g_wc1[2048];
__device__ __align__(16) float g_bc1[64];
__device__ __align__(16) float g_wc2[8192];
__device__ __align__(16) float g_bc2[128];
__device__ __align__(16) float g_wps1[32768];
__device__ __align__(16) float g_bps1[256];
__device__ __align__(16) float g_wps2[32768];
__device__ __align__(16) float g_bps2[128];
__device__ __align__(16) float g_wp1[192];
__device__ __align__(16) float g_bp1[64];
__device__ __align__(16) float g_wp2[8192];
__device__ __align__(16) float g_bp2[128];
__device__ __align__(16) float g_wfc1[16384];
__device__ __align__(16) float g_bfc1[64];
__device__ __align__(16) float g_wfc2[10240];
__device__ __align__(16) float g_bfc2[64];
__device__ __align__(16) float g_wfc[8192];
__device__ __align__(16) float g_bfc[64];

__device__ __align__(16) float g_cfw[NN*128];
__device__ __align__(16) float g_Yw[NN*128];
__device__ __align__(16) float g_Zw[NN*128];
__device__ __align__(16) float g_logA[4000];   // exp(-dist) numerators
__device__ __align__(16) float g_logB[4000];
__device__ int   g_inds[4000];
__device__ int   g_inds_tc[4000];
__device__ float g_sumA;                       // softmax denominators (atomic)
__device__ float g_sumB;

// two-level grid barrier state. Counters return to 0 after each barrier;
// gen grows monotonically -> correct across graph replays without host reset.
__device__ int g_leaf_cnt[NLEAF*16];           // 64B-padded per-leaf counters
__device__ int g_bar_cnt = 0;
__device__ int g_bar_gen = 0;

__device__ __forceinline__ float b2f(us u){ return __uint_as_float(((u32)u)<<16); }
__device__ __forceinline__ us f2b(float f){
  u32 u = __float_as_uint(f);
  u32 r = u + 0x7fffu + ((u>>16)&1u);
  return (us)(r>>16);
}
__device__ __forceinline__ float lrelu(float x){ return x >= 0.f ? x : SLOPEC*x; }
__device__ __forceinline__ float dot4(const float4 w, const float* h){
  return w.x*h[0] + w.y*h[1] + w.z*h[2] + w.w*h[3];
}
__device__ __forceinline__ int clampi(int v){ return v < 0 ? 0 : (v >= NN ? NN-1 : v); }

// Device-scope two-level grid barrier. Safe because all NBLK blocks are
// co-resident by construction (see NBLK comment).
__device__ __forceinline__ void grid_barrier(){
  __syncthreads();
  if (threadIdx.x == 0){
    __threadfence();   // release: make this block's writes device-visible
    int gen = __hip_atomic_load(&g_bar_gen, __ATOMIC_RELAXED, __HIP_MEMORY_SCOPE_AGENT);
    const int leaf = (blockIdx.x & (NLEAF-1))*16;
    int prev = __hip_atomic_fetch_add(&g_leaf_cnt[leaf], 1, __ATOMIC_ACQ_REL, __HIP_MEMORY_SCOPE_AGENT);
    if (prev == (NBLK/NLEAF)-1){
      __hip_atomic_store(&g_leaf_cnt[leaf], 0, __ATOMIC_RELAXED, __HIP_MEMORY_SCOPE_AGENT);
      int p2 = __hip_atomic_fetch_add(&g_bar_cnt, 1, __ATOMIC_ACQ_REL, __HIP_MEMORY_SCOPE_AGENT);
      if (p2 == NLEAF-1){
        __hip_atomic_store(&g_bar_cnt, 0, __ATOMIC_RELAXED, __HIP_MEMORY_SCOPE_AGENT);
        __hip_atomic_fetch_add(&g_bar_gen, 1, __ATOMIC_RELEASE, __HIP_MEMORY_SCOPE_AGENT);
      }
    }
    while (__hip_atomic_load(&g_bar_gen, __ATOMIC_RELAXED, __HIP_MEMORY_SCOPE_AGENT) == gen)
      __builtin_amdgcn_s_sleep(2);
    __threadfence();   // acquire: invalidate caches before reading others' data
  }
  __syncthreads();
}

// ONE persistent kernel, 768 blocks:
//   phase 0: dtype-detect + convert all inputs to fp32 device globals
//   barrier
//   phase 1: blocks 0..249   = KNN (4 queries) + exp numerators + atomic denom
//            blocks 250..749 = per-point conv chains (ONE point per block)
//   barrier
//   phase 2: blocks 0..499   = weighted gather-mean + fc chain -> out
__global__ __launch_bounds__(256, 4) void kall(
    const void* in0, const void* in1, const void* in2, const void* in3,
    const void* in4, const void* in5, const void* in6, const void* in7,
    const void* in8, const void* in9, const void* in10, const void* in11,
    const void* in12, const void* in13, const void* in14, const void* in15,
    const void* in16, const void* in17, const void* in18, const void* in19,
    const void* in20, void* outv)
{
  __shared__ __align__(16) float sm[1504];
  __shared__ float s_wsum[4];
  __shared__ int sflag;
  const int tid = threadIdx.x;
  const int b = blockIdx.x;

  // ---------------- phase 0: detect + convert ----------------
  if (tid < 64){
    const us* u = (const us*)in0;
    int cnt = 0;
    #pragma unroll
    for (int j = 0; j < 8; ++j){
      us v = u[2*(tid*8+j)];          // even us-index: fp32 low-halves if fp32
      int e = (v >> 7) & 0xff;
      cnt += (e >= 143);              // |x| >= 2^16 as bf16: impossible for real data
    }
    #pragma unroll
    for (int off = 32; off; off >>= 1) cnt += __shfl_xor(cnt, off);
    if (tid == 0) sflag = (cnt > 16);
  }
  if (b == 0 && tid == 0){ g_sumA = 0.f; g_sumB = 0.f; }
  __syncthreads();
  const int isf32 = sflag;
  {
    const int g0 = b*256 + tid;
    const int gs = NBLK*256;          // 196608 >= every array size: single pass
    #define CVT(src, dst, n) \
      for (int i = g0; i < (n); i += gs) \
        dst[i] = isf32 ? ((const float*)(src))[i] : b2f(((const us*)(src))[i]);
    CVT(in0,  g_imf, 16000)
    CVT(in1,  g_c,   1500)
    CVT(in2,  g_ct,  1500)
    CVT(in3,  g_wc1, 2048)
    CVT(in4,  g_bc1, 64)
    CVT(in5,  g_wc2, 8192)
    CVT(in6,  g_bc2, 128)
    CVT(in7,  g_wps1,32768)
    CVT(in8,  g_bps1,256)
    CVT(in9,  g_wps2,32768)
    CVT(in10, g_bps2,128)
    CVT(in11, g_wp1, 192)
    CVT(in12, g_bp1, 64)
    CVT(in13, g_wp2, 8192)
    CVT(in14, g_bp2, 128)
    CVT(in15, g_wfc1,16384)
    CVT(in16, g_bfc1,64)
    CVT(in17, g_wfc2,10240)
    CVT(in18, g_bfc2,64)
    CVT(in19, g_wfc, 8192)
    CVT(in20, g_bfc, 64)
    #undef CVT
  }

  grid_barrier();

  // ---------------- phase 1 ----------------
  if (b < 250) {
    // KNN: 1 query per wave, 4 per block; indices + exp(-dist) + denom partials
    const int dir = (b >= 125);            // 0: query=c, ref=ct ; 1: query=ct, ref=c
    const float* refp = dir ? g_c : g_ct;
    const float* qp   = dir ? g_ct : g_c;
    int* outp = dir ? g_inds_tc : g_inds;
    float* logp = dir ? g_logB : g_logA;
    for (int e = tid; e < 1500; e += 256) sm[e] = refp[e];
    __syncthreads();
    const int lane = tid & 63;
    const int wv = tid >> 6;
    const int q = b*4 + wv;
    const int qi = q - (dir ? 500 : 0);
    float qx = qp[qi*3+0], qy = qp[qi*3+1], qz = qp[qi*3+2];
    // exact numpy op order: sum(q^2) - 2*dot + sum(r^2)
    float sq = __fadd_rn(__fadd_rn(__fmul_rn(qx,qx),__fmul_rn(qy,qy)),__fmul_rn(qz,qz));
    const u64 SENT = 0xFFFFFFFF00000000ull;   // sentinel carries valid idx 0
    u64 a0=SENT,a1=SENT,a2=SENT,a3=SENT,a4=SENT,a5=SENT,a6=SENT,a7=SENT;
    for (int j = lane; j < NN; j += 64){
      float rx = sm[j*3+0], ry = sm[j*3+1], rz = sm[j*3+2];
      float dt = __fadd_rn(__fadd_rn(__fmul_rn(qx,rx),__fmul_rn(qy,ry)),__fmul_rn(qz,rz));
      float sr = __fadd_rn(__fadd_rn(__fmul_rn(rx,rx),__fmul_rn(ry,ry)),__fmul_rn(rz,rz));
      float d2 = __fadd_rn(__fsub_rn(sq, __fmul_rn(2.f,dt)), sr);
      u32 fb = __float_as_uint(d2);
      fb = (fb & 0x80000000u) ? ~fb : (fb | 0x80000000u);   // monotone float->uint
      u64 key = ((u64)fb << 32) | (u32)j;
      if (key < a0){ u64 t=a0; a0=key; key=t; }
      if (key < a1){ u64 t=a1; a1=key; key=t; }
      if (key < a2){ u64 t=a2; a2=key; key=t; }
      if (key < a3){ u64 t=a3; a3=key; key=t; }
      if (key < a4){ u64 t=a4; a4=key; key=t; }
      if (key < a5){ u64 t=a5; a5=key; key=t; }
      if (key < a6){ u64 t=a6; a6=key; key=t; }
      if (key < a7){ u64 t=a7; a7=key; key=t; }
    }
    float wsum = 0.f;
    #pragma unroll
    for (int r8 = 0; r8 < 8; ++r8){
      u64 m = a0;
      #pragma unroll
      for (int off = 32; off; off >>= 1){
        u64 o = __shfl_xor(m, off);
        if (o < m) m = o;
      }
      bool mine = (a0 == m);
      a0 = mine ? a1 : a0;  a1 = mine ? a2 : a1;  a2 = mine ? a3 : a2;
      a3 = mine ? a4 : a3;  a4 = mine ? a5 : a4;  a5 = mine ? a6 : a5;
      a6 = mine ? a7 : a6;  a7 = mine ? SENT : a7;
      if (lane == 0){
        int idx = (int)(m & 0xffffffffu);
        outp[qi*8 + r8] = idx;
        // softmax numerator exp(-dist), reference dist order
        float rx = sm[idx*3+0], ry = sm[idx*3+1], rz = sm[idx*3+2];
        float dx = __fsub_rn(qx,rx), dy = __fsub_rn(qy,ry), dz = __fsub_rn(qz,rz);
        float s2 = __fadd_rn(__fadd_rn(__fmul_rn(dx,dx),__fmul_rn(dy,dy)),__fmul_rn(dz,dz));
        float v = expf(-sqrtf(s2));   // in [4.5e-5,1]: shift-free safe
        logp[qi*8 + r8] = v;
        wsum += v;
      }
    }
    if (lane == 0) s_wsum[wv] = wsum;
    __syncthreads();
    if (tid == 0){
      float bs = (s_wsum[0] + s_wsum[1]) + (s_wsum[2] + s_wsum[3]);
      atomicAdd(dir ? &g_sumB : &g_sumA, bs);
    }
  } else if (b < 750) {
    // ---------------- per-point conv chain, ONE point per block ----------------
    const int p = b - 250;
    float* sx  = sm;          // 3   (c column)
    float* sxi = sm + 4;      // 32  (imf column)
    float* h1  = sm + 64;     // 64
    float* cf  = sm + 128;    // 128
    float* h2  = sm + 256;    // 256
    float* hy  = sm + 512;    // 64
    if (tid < 3)  sx[tid] = g_c[p*3 + tid];
    if (tid >= 32 && tid < 64) sxi[tid-32] = g_imf[(tid-32)*NN + p];
    __syncthreads();
    // stage1: h1 = lrelu(pconv1 @ x + b)   (threads 0..63)
    if (tid < 64){
      float acc = g_bp1[tid];
      acc += g_wp1[tid*3+0]*sx[0];
      acc += g_wp1[tid*3+1]*sx[1];
      acc += g_wp1[tid*3+2]*sx[2];
      h1[tid] = lrelu(acc);
    }
    __syncthreads();
    // stage2 (t0..127): cf = pconv2 @ h1 + b  (dot64, 2 accumulators)
    // stage5 (t128..191): hy = lrelu(conv1 @ imf + b)  (dot32) — independent
    if (tid < 128){
      int r = tid;
      float aA = g_bp2[r], aB = 0.f;
      const float4* wrow = (const float4*)(g_wp2 + (size_t)r*64);
      #pragma unroll 8
      for (int c4=0; c4<16; c4+=2){
        aA += dot4(wrow[c4],   h1 + c4*4);
        aB += dot4(wrow[c4+1], h1 + c4*4 + 4);
      }
      float acc = aA + aB;
      cf[r] = acc;
      g_cfw[(size_t)p*128 + r] = acc;
    } else if (tid < 192){
      int r = tid - 128;
      float aA = g_bc1[r], aB = 0.f;
      const float4* wrow = (const float4*)(g_wc1 + (size_t)r*32);
      #pragma unroll 4
      for (int c4=0; c4<8; c4+=2){
        aA += dot4(wrow[c4],   sxi + c4*4);
        aB += dot4(wrow[c4+1], sxi + c4*4 + 4);
      }
      hy[r] = lrelu(aA + aB);
    }
    __syncthreads();
    // stage3 (all 256): h2 = lrelu(psconv1 @ cf + b)  (dot128, 2 accumulators)
    {
      float aA = g_bps1[tid], aB = 0.f;
      const float4* wrow = (const float4*)(g_wps1 + (size_t)tid*128);
      #pragma unroll 8
      for (int c4=0; c4<32; c4+=2){
        aA += dot4(wrow[c4],   cf + c4*4);
        aB += dot4(wrow[c4+1], cf + c4*4 + 4);
      }
      h2[tid] = lrelu(aA + aB);
    }
    __syncthreads();
    // stage4 (t0..127): Z = psconv2 @ h2 + b  (dot256, 4 accumulators)
    // stage6 (t128..255): Y = conv2 @ hy + b  (dot64, 2 accumulators)
    if (tid < 128){
      int r = tid;
      float aA = g_bps2[r], aB = 0.f, aC = 0.f, aD = 0.f;
      const float4* wrow = (const float4*)(g_wps2 + (size_t)r*256);
      #pragma unroll 8
      for (int c4=0; c4<64; c4+=4){
        aA += dot4(wrow[c4],   h2 + c4*4);
        aB += dot4(wrow[c4+1], h2 + c4*4 + 4);
        aC += dot4(wrow[c4+2], h2 + c4*4 + 8);
        aD += dot4(wrow[c4+3], h2 + c4*4 + 12);
      }
      g_Zw[(size_t)p*128 + r] = (aA + aB) + (aC + aD);
    } else {
      int r = tid - 128;
      float aA = g_bc2[r], aB = 0.f;
      const float4* wrow = (const float4*)(g_wc2 + (size_t)r*64);
      #pragma unroll 8
      for (int c4=0; c4<16; c4+=2){
        aA += dot4(wrow[c4],   hy + c4*4);
        aB += dot4(wrow[c4+1], hy + c4*4 + 4);
      }
      g_Yw[(size_t)p*128 + r] = aA + aB;
    }
  }

  grid_barrier();

  // ---------------- phase 2: gather-mean + fc chain, blocks 0..499 ----------------
  if (b < NN){
    float* sb1 = sm;          // 256 : [sf | cf]
    float* sb2 = sm + 256;    // 160 : [sfp | imf]
    float* sg  = sm + 416;    // 128 : lrelu([f2 ; f1])
    float* swa = sm + 544;    // 8
    float* swb = sm + 552;    // 8
    int* sia = (int*)(sm + 560);  // 8
    int* sib = (int*)(sm + 568);  // 8
    const int p = b;
    if (tid < 8){
      sia[tid] = clampi(g_inds[p*8 + tid]);
      sib[tid] = clampi(g_inds_tc[p*8 + tid]);
      float totA = g_sumA, totB = g_sumB;   // precomputed in phase 1
      swa[tid] = g_logA[p*8 + tid] / totA;
      swb[tid] = g_logB[p*8 + tid] / totB;
    }
    if (tid >= 64 && tid < 192)  sb1[128 + (tid-64)]  = g_cfw[(size_t)p*128 + (tid-64)];
    if (tid >= 192 && tid < 224) sb2[128 + (tid-192)] = g_imf[(tid-192)*NN + p];
    __syncthreads();
    // gather-mean: t0..127 -> sf (from Y), t128..255 -> sfp (from Z)
    if (tid < 128){
      int r = tid;
      float acc = 0.f;
      #pragma unroll
      for (int j=0;j<8;++j) acc += swa[j] * g_Yw[(size_t)sia[j]*128 + r];
      sb1[r] = acc * 0.125f;
    } else {
      int r = tid - 128;
      float acc = 0.f;
      #pragma unroll
      for (int j=0;j<8;++j) acc += swb[j] * g_Zw[(size_t)sib[j]*128 + r];
      sb2[r] = acc * 0.125f;
    }
    __syncthreads();
    // f1 (t0..63, dot256, 4 acc) ; f2 (t64..127, dot160, 2 acc); g = lrelu([f2 ; f1])
    if (tid < 64){
      int r = tid;
      float aA = g_bfc1[r], aB = 0.f, aC = 0.f, aD = 0.f;
      const float4* w1 = (const float4*)(g_wfc1 + (size_t)r*256);
      #pragma unroll 8
      for (int c4=0; c4<64; c4+=4){
        aA += dot4(w1[c4],   sb1 + c4*4);
        aB += dot4(w1[c4+1], sb1 + c4*4 + 4);
        aC += dot4(w1[c4+2], sb1 + c4*4 + 8);
        aD += dot4(w1[c4+3], sb1 + c4*4 + 12);
      }
      sg[64 + r] = lrelu((aA + aB) + (aC + aD));
    } else if (tid < 128){
      int r = tid - 64;
      float aA = g_bfc2[r], aB = 0.f;
      const float4* w2 = (const float4*)(g_wfc2 + (size_t)r*160);
      #pragma unroll 8
      for (int c4=0; c4<40; c4+=2){
        aA += dot4(w2[c4],   sb2 + c4*4);
        aB += dot4(w2[c4+1], sb2 + c4*4 + 4);
      }
      sg[r] = lrelu(aA + aB);
    }
    __syncthreads();
    // out = wfc @ g + b (t0..63, dot128, 2 acc)
    if (tid < 64){
      int r = tid;
      float aA = g_bfc[r], aB = 0.f;
      const float4* w3 = (const float4*)(g_wfc + (size_t)r*128);
      #pragma unroll 8
      for (int c4=0; c4<32; c4+=2){
        aA += dot4(w3[c4],   sg + c4*4);
        aB += dot4(w3[c4+1], sg + c4*4 + 4);
      }
      float a = aA + aB;
      if (isf32) ((float*)outv)[r*NN + p] = a;
      else       ((us*)outv)[r*NN + p] = f2b(a);
    }
  }
}

extern "C" void kernel_launch(void* const* d_in, const int* in_sizes, int n_in,
                              void* d_out, int out_size, void* d_ws, size_t ws_size,
                              hipStream_t stream)
{
  (void)d_ws; (void)ws_size; (void)in_sizes; (void)n_in; (void)out_size;
  kall<<<NBLK, 256, 0, stream>>>(
    d_in[0], d_in[1], d_in[2], d_in[3], d_in[4], d_in[5], d_in[6],
    d_in[7], d_in[8], d_in[9], d_in[10], d_in[11], d_in[12], d_in[13],
    d_in[14], d_in[15], d_in[16], d_in[17], d_in[18], d_in[19], d_in[20],
    d_out);
}

// Round 4
// 140.514 us; speedup vs baseline: 1.5755x; 1.5755x over previous
//
#include <hip/hip_runtime.h>

#define NN 500
#define SLOPEC 0.01f

typedef unsigned short us;
typedef unsigned int u32;
typedef unsigned long long u64;

// ---- canonical fp32 copies of all inputs + scratch, as device globals ----
// (16B-aligned by construction: safe for float4 loads. Harness input buffers
//  are NOT guaranteed 16B-aligned — inputs only ever read with scalar loads in k0.)
__device__ __align__(16) float g_imf[16000];
__device__ __align__(16) float g_c[1504];
__device__ __align__(16) float g_ct[1504];
__device__ __align__(16) float g_wc1[2048];
__device__ __align__(16) float g_bc1[64];
__device__ __align__(16) float g_wc2[8192];
__device__ __align__(16) float g_bc2[128];
__device__ __align__(16) float g_wps1[32768];
__device__ __align__(16) float g_bps1[256];
__device__ __align__(16) float g_wps2[32768];
__device__ __align__(16) float g_bps2[128];
__device__ __align__(16) float g_wp1[192];
__device__ __align__(16) float g_bp1[64];
__device__ __align__(16) float g_wp2[8192];
__device__ __align__(16) float g_bp2[128];
__device__ __align__(16) float g_wfc1[16384];
__device__ __align__(16) float g_bfc1[64];
__device__ __align__(16) float g_wfc2[10240];
__device__ __align__(16) float g_bfc2[64];
__device__ __align__(16) float g_wfc[8192];
__device__ __align__(16) float g_bfc[64];

__device__ __align__(16) float g_cfw[NN*128];
__device__ __align__(16) float g_Yw[NN*128];
__device__ __align__(16) float g_Zw[NN*128];
__device__ __align__(16) float g_logA[4000];   // exp(-dist) numerators (k1)
__device__ __align__(16) float g_logB[4000];
__device__ int   g_inds[4000];
__device__ int   g_inds_tc[4000];
__device__ int   g_isf32;
// softmax denominator partials (8-way split to avoid same-address atomic
// serialization; k3 sums the 8 scalars). Zeroed by k0 each launch.
__device__ __align__(16) float g_sumA8[8];
__device__ __align__(16) float g_sumB8[8];

__device__ __forceinline__ float b2f(us u){ return __uint_as_float(((u32)u)<<16); }
__device__ __forceinline__ us f2b(float f){
  u32 u = __float_as_uint(f);
  u32 r = u + 0x7fffu + ((u>>16)&1u);
  return (us)(r>>16);
}
__device__ __forceinline__ float lrelu(float x){ return x >= 0.f ? x : SLOPEC*x; }
__device__ __forceinline__ float dot4(const float4 w, const float* h){
  return w.x*h[0] + w.y*h[1] + w.z*h[2] + w.w*h[3];
}
__device__ __forceinline__ int clampi(int v){ return v < 0 ? 0 : (v >= NN ? NN-1 : v); }

// K0: detect input dtype (fp32 vs bf16), convert every input into canonical
// fp32 device-global arrays (scalar loads only), zero denominator partials.
__global__ __launch_bounds__(256) void k0(
    const void* in0, const void* in1, const void* in2, const void* in3,
    const void* in4, const void* in5, const void* in6, const void* in7,
    const void* in8, const void* in9, const void* in10, const void* in11,
    const void* in12, const void* in13, const void* in14, const void* in15,
    const void* in16, const void* in17, const void* in18, const void* in19,
    const void* in20)
{
  __shared__ int sflag;
  const int tid = threadIdx.x;
  if (tid < 64){
    const us* u = (const us*)in0;
    int cnt = 0;
    #pragma unroll
    for (int j = 0; j < 8; ++j){
      us v = u[2*(tid*8+j)];          // even us-index: fp32 low-halves if fp32
      int e = (v >> 7) & 0xff;
      cnt += (e >= 143);              // |x| >= 2^16 as bf16: impossible for real data
    }
    #pragma unroll
    for (int off = 32; off; off >>= 1) cnt += __shfl_xor(cnt, off);
    if (tid == 0){ sflag = (cnt > 16); g_isf32 = (cnt > 16); }
  }
  if (blockIdx.x == 0 && tid < 8){ g_sumA8[tid] = 0.f; g_sumB8[tid] = 0.f; }
  __syncthreads();
  const int isf32 = sflag;
  const int g0 = blockIdx.x*256 + tid;
  const int gs = gridDim.x*256;
  #define CVT(src, dst, n) \
    for (int i = g0; i < (n); i += gs) \
      dst[i] = isf32 ? ((const float*)(src))[i] : b2f(((const us*)(src))[i]);
  CVT(in0,  g_imf, 16000)
  CVT(in1,  g_c,   1500)
  CVT(in2,  g_ct,  1500)
  CVT(in3,  g_wc1, 2048)
  CVT(in4,  g_bc1, 64)
  CVT(in5,  g_wc2, 8192)
  CVT(in6,  g_bc2, 128)
  CVT(in7,  g_wps1,32768)
  CVT(in8,  g_bps1,256)
  CVT(in9,  g_wps2,32768)
  CVT(in10, g_bps2,128)
  CVT(in11, g_wp1, 192)
  CVT(in12, g_bp1, 64)
  CVT(in13, g_wp2, 8192)
  CVT(in14, g_bp2, 128)
  CVT(in15, g_wfc1,16384)
  CVT(in16, g_bfc1,64)
  CVT(in17, g_wfc2,10240)
  CVT(in18, g_bfc2,64)
  CVT(in19, g_wfc, 8192)
  CVT(in20, g_bfc, 64)
  #undef CVT
}

// K1: blocks 0..249   = KNN (1 query per wave, 4/block) + exp(-dist) + denom partials.
//     blocks 250..374 = per-point conv chains, FOUR points per block:
//                       each thread loads its weight row once and runs 2-4
//                       independent FMA chains (ILP + 4x weight amortization).
__global__ __launch_bounds__(256) void k1()
{
  __shared__ __align__(16) float sm[2192];
  __shared__ float s_wsum[4];
  const int tid = threadIdx.x;
  const int b = blockIdx.x;
  if (b < 250) {
    // ---------------- KNN + exp numerators (verbatim-proven path) ----------------
    const int dir = (b >= 125);            // 0: query=c, ref=ct ; 1: query=ct, ref=c
    const float* refp = dir ? g_c : g_ct;
    const float* qp   = dir ? g_ct : g_c;
    int* outp = dir ? g_inds_tc : g_inds;
    float* logp = dir ? g_logB : g_logA;
    for (int e = tid; e < 1500; e += 256) sm[e] = refp[e];
    __syncthreads();
    const int lane = tid & 63;
    const int wv = tid >> 6;
    const int q = b*4 + wv;
    const int qi = q - (dir ? 500 : 0);
    float qx = qp[qi*3+0], qy = qp[qi*3+1], qz = qp[qi*3+2];
    // exact numpy op order: sum(q^2) - 2*dot + sum(r^2)
    float sq = __fadd_rn(__fadd_rn(__fmul_rn(qx,qx),__fmul_rn(qy,qy)),__fmul_rn(qz,qz));
    const u64 SENT = 0xFFFFFFFF00000000ull;   // sentinel carries valid idx 0
    u64 a0=SENT,a1=SENT,a2=SENT,a3=SENT,a4=SENT,a5=SENT,a6=SENT,a7=SENT;
    for (int j = lane; j < NN; j += 64){
      float rx = sm[j*3+0], ry = sm[j*3+1], rz = sm[j*3+2];
      float dt = __fadd_rn(__fadd_rn(__fmul_rn(qx,rx),__fmul_rn(qy,ry)),__fmul_rn(qz,rz));
      float sr = __fadd_rn(__fadd_rn(__fmul_rn(rx,rx),__fmul_rn(ry,ry)),__fmul_rn(rz,rz));
      float d2 = __fadd_rn(__fsub_rn(sq, __fmul_rn(2.f,dt)), sr);
      u32 fb = __float_as_uint(d2);
      fb = (fb & 0x80000000u) ? ~fb : (fb | 0x80000000u);   // monotone float->uint
      u64 key = ((u64)fb << 32) | (u32)j;
      if (key < a0){ u64 t=a0; a0=key; key=t; }
      if (key < a1){ u64 t=a1; a1=key; key=t; }
      if (key < a2){ u64 t=a2; a2=key; key=t; }
      if (key < a3){ u64 t=a3; a3=key; key=t; }
      if (key < a4){ u64 t=a4; a4=key; key=t; }
      if (key < a5){ u64 t=a5; a5=key; key=t; }
      if (key < a6){ u64 t=a6; a6=key; key=t; }
      if (key < a7){ u64 t=a7; a7=key; key=t; }
    }
    float wsum = 0.f;
    #pragma unroll
    for (int r8 = 0; r8 < 8; ++r8){
      u64 m = a0;
      #pragma unroll
      for (int off = 32; off; off >>= 1){
        u64 o = __shfl_xor(m, off);
        if (o < m) m = o;
      }
      bool mine = (a0 == m);
      a0 = mine ? a1 : a0;  a1 = mine ? a2 : a1;  a2 = mine ? a3 : a2;
      a3 = mine ? a4 : a3;  a4 = mine ? a5 : a4;  a5 = mine ? a6 : a5;
      a6 = mine ? a7 : a6;  a7 = mine ? SENT : a7;
      if (lane == 0){
        int idx = (int)(m & 0xffffffffu);
        outp[qi*8 + r8] = idx;
        // softmax numerator exp(-dist), reference dist order
        float rx = sm[idx*3+0], ry = sm[idx*3+1], rz = sm[idx*3+2];
        float dx = __fsub_rn(qx,rx), dy = __fsub_rn(qy,ry), dz = __fsub_rn(qz,rz);
        float s2 = __fadd_rn(__fadd_rn(__fmul_rn(dx,dx),__fmul_rn(dy,dy)),__fmul_rn(dz,dz));
        float v = expf(-sqrtf(s2));   // in [4.5e-5,1]: shift-free safe
        logp[qi*8 + r8] = v;
        wsum += v;
      }
    }
    if (lane == 0) s_wsum[wv] = wsum;
    __syncthreads();
    if (tid == 0){
      float bs = (s_wsum[0] + s_wsum[1]) + (s_wsum[2] + s_wsum[3]);
      atomicAdd((dir ? g_sumB8 : g_sumA8) + (b & 7), bs);
    }
  } else {
    // ---------------- conv chains, FOUR points per block ----------------
    const int p0 = (b - 250)*4;
    float* sx  = sm;           // [4][4]   c columns
    float* sxi = sm + 16;      // [4][32]  imf columns
    float* h1  = sm + 144;     // [4][64]
    float* hy  = sm + 400;     // [4][64]
    float* cf  = sm + 656;     // [4][128]
    float* h2  = sm + 1168;    // [4][256]
    if (tid < 16){
      int pt = tid >> 2, j = tid & 3;
      if (j < 3) sx[pt*4 + j] = g_c[(p0+pt)*3 + j];
    } else if (tid >= 32 && tid < 160){
      int t = tid - 32, pt = t >> 5, ch = t & 31;
      sxi[pt*32 + ch] = g_imf[ch*NN + p0 + pt];
    }
    __syncthreads();
    // Stage A (all 256: row=tid&63, pt=tid>>6):
    //   h1[pt][r] = lrelu(pconv1 @ x + b)   (3 FMAs)
    //   hy[pt][r] = lrelu(conv1 @ imf + b)  (dot32, 2 acc)
    {
      int r = tid & 63, pt = tid >> 6;
      float acc = g_bp1[r];
      acc += g_wp1[r*3+0]*sx[pt*4+0];
      acc += g_wp1[r*3+1]*sx[pt*4+1];
      acc += g_wp1[r*3+2]*sx[pt*4+2];
      h1[pt*64 + r] = lrelu(acc);
      float aA = g_bc1[r], aB = 0.f;
      const float4* wrow = (const float4*)(g_wc1 + (size_t)r*32);
      const float* hp = sxi + pt*32;
      #pragma unroll 4
      for (int c4=0; c4<8; c4+=2){
        aA += dot4(wrow[c4],   hp + c4*4);
        aB += dot4(wrow[c4+1], hp + c4*4 + 4);
      }
      hy[pt*64 + r] = lrelu(aA + aB);
    }
    __syncthreads();
    // Stage B (row=tid&127, point-pair pg=(tid>>7)*2):
    //   cf = pconv2 @ h1 + b (dot64, 2 acc per point, weight row loaded once)
    //   Y  = conv2  @ hy + b (dot64, 2 acc per point) — independent, same region
    {
      int r = tid & 127, pg = (tid >> 7)*2;
      const float4* wrow = (const float4*)(g_wp2 + (size_t)r*64);
      const float* hA = h1 + pg*64;
      const float* hB = h1 + (pg+1)*64;
      float aA = g_bp2[r], aA2 = 0.f, aB = g_bp2[r], aB2 = 0.f;
      #pragma unroll 8
      for (int c4=0; c4<16; c4+=2){
        float4 w0 = wrow[c4], w1 = wrow[c4+1];
        aA += dot4(w0, hA + c4*4);  aA2 += dot4(w1, hA + c4*4 + 4);
        aB += dot4(w0, hB + c4*4);  aB2 += dot4(w1, hB + c4*4 + 4);
      }
      float vA = aA + aA2, vB = aB + aB2;
      cf[pg*128 + r] = vA;       g_cfw[(size_t)(p0+pg)*128 + r] = vA;
      cf[(pg+1)*128 + r] = vB;   g_cfw[(size_t)(p0+pg+1)*128 + r] = vB;
      const float4* wy = (const float4*)(g_wc2 + (size_t)r*64);
      const float* yA = hy + pg*64;
      const float* yB = hy + (pg+1)*64;
      float cA = g_bc2[r], cA2 = 0.f, cB = g_bc2[r], cB2 = 0.f;
      #pragma unroll 8
      for (int c4=0; c4<16; c4+=2){
        float4 w0 = wy[c4], w1 = wy[c4+1];
        cA += dot4(w0, yA + c4*4);  cA2 += dot4(w1, yA + c4*4 + 4);
        cB += dot4(w0, yB + c4*4);  cB2 += dot4(w1, yB + c4*4 + 4);
      }
      g_Yw[(size_t)(p0+pg)*128 + r]   = cA + cA2;
      g_Yw[(size_t)(p0+pg+1)*128 + r] = cB + cB2;
    }
    __syncthreads();
    // Stage C (row=tid): h2 = lrelu(psconv1 @ cf + b) for all 4 points
    // (dot128, 2 acc per point; weight row loaded ONCE for 4 chains)
    {
      const float4* wrow = (const float4*)(g_wps1 + (size_t)tid*128);
      float a0_ = g_bps1[tid], a0b = 0.f;
      float a1_ = g_bps1[tid], a1b = 0.f;
      float a2_ = g_bps1[tid], a2b = 0.f;
      float a3_ = g_bps1[tid], a3b = 0.f;
      #pragma unroll 8
      for (int c4=0; c4<32; c4+=2){
        float4 w0 = wrow[c4], w1 = wrow[c4+1];
        a0_ += dot4(w0, cf + c4*4);          a0b += dot4(w1, cf + c4*4 + 4);
        a1_ += dot4(w0, cf + 128 + c4*4);    a1b += dot4(w1, cf + 128 + c4*4 + 4);
        a2_ += dot4(w0, cf + 256 + c4*4);    a2b += dot4(w1, cf + 256 + c4*4 + 4);
        a3_ += dot4(w0, cf + 384 + c4*4);    a3b += dot4(w1, cf + 384 + c4*4 + 4);
      }
      h2[tid]       = lrelu(a0_ + a0b);
      h2[256 + tid] = lrelu(a1_ + a1b);
      h2[512 + tid] = lrelu(a2_ + a2b);
      h2[768 + tid] = lrelu(a3_ + a3b);
    }
    __syncthreads();
    // Stage D (row=tid&127, pg=(tid>>7)*2): Z = psconv2 @ h2 + b
    // (dot256, 2 acc per point, 2 points per thread)
    {
      int r = tid & 127, pg = (tid >> 7)*2;
      const float4* wrow = (const float4*)(g_wps2 + (size_t)r*256);
      const float* hA = h2 + pg*256;
      const float* hB = h2 + (pg+1)*256;
      float aA = g_bps2[r], aA2 = 0.f, aB = g_bps2[r], aB2 = 0.f;
      #pragma unroll 8
      for (int c4=0; c4<64; c4+=2){
        float4 w0 = wrow[c4], w1 = wrow[c4+1];
        aA += dot4(w0, hA + c4*4);  aA2 += dot4(w1, hA + c4*4 + 4);
        aB += dot4(w0, hB + c4*4);  aB2 += dot4(w1, hB + c4*4 + 4);
      }
      g_Zw[(size_t)(p0+pg)*128 + r]   = aA + aA2;
      g_Zw[(size_t)(p0+pg+1)*128 + r] = aB + aB2;
    }
  }
}

// K3: FOUR points per block (125 blocks): weighted gather-mean + fc chain -> out.
// Weight rows shared by the 4 threads handling the same row (L1-hot).
__global__ __launch_bounds__(256) void k3(void* outv)
{
  __shared__ __align__(16) float sm[2304];
  float* sb1 = sm;              // [4][256] : [sf | cf]
  float* sb2 = sm + 1024;       // [4][160] : [sfp | imf]
  float* sg  = sm + 1664;       // [4][128] : lrelu([f2 ; f1])
  float* swa = sm + 2176;       // [4][8]
  float* swb = sm + 2208;       // [4][8]
  int* sia = (int*)(sm + 2240); // [4][8]
  int* sib = (int*)(sm + 2272); // [4][8]
  const int tid = threadIdx.x;
  const int p0 = blockIdx.x*4;
  const int of32 = g_isf32;
  // ---- staging ----
  if (tid < 32){
    int pt = tid >> 3, j = tid & 7, p = p0 + pt;
    sia[tid] = clampi(g_inds[p*8 + j]);
    sib[tid] = clampi(g_inds_tc[p*8 + j]);
    float totA = ((g_sumA8[0]+g_sumA8[1])+(g_sumA8[2]+g_sumA8[3]))
               + ((g_sumA8[4]+g_sumA8[5])+(g_sumA8[6]+g_sumA8[7]));
    float totB = ((g_sumB8[0]+g_sumB8[1])+(g_sumB8[2]+g_sumB8[3]))
               + ((g_sumB8[4]+g_sumB8[5])+(g_sumB8[6]+g_sumB8[7]));
    swa[tid] = g_logA[p*8 + j] / totA;
    swb[tid] = g_logB[p*8 + j] / totB;
  }
  {
    int r = tid & 127, pg = (tid >> 7)*2;
    sb1[pg*256 + 128 + r]     = g_cfw[(size_t)(p0+pg)*128 + r];
    sb1[(pg+1)*256 + 128 + r] = g_cfw[(size_t)(p0+pg+1)*128 + r];
  }
  if (tid < 128){
    int pt = tid >> 5, ch = tid & 31;
    sb2[pt*160 + 128 + ch] = g_imf[ch*NN + p0 + pt];
  }
  __syncthreads();
  // ---- gather-mean: each thread does row r for 2 points, sf and sfp ----
  {
    int r = tid & 127, pg = (tid >> 7)*2;
    #pragma unroll 2
    for (int q = pg; q < pg+2; ++q){
      float acc = 0.f;
      #pragma unroll
      for (int j=0;j<8;++j) acc += swa[q*8+j] * g_Yw[(size_t)sia[q*8+j]*128 + r];
      sb1[q*256 + r] = acc * 0.125f;
      float acp = 0.f;
      #pragma unroll
      for (int j=0;j<8;++j) acp += swb[q*8+j] * g_Zw[(size_t)sib[q*8+j]*128 + r];
      sb2[q*160 + r] = acp * 0.125f;
    }
  }
  __syncthreads();
  // ---- fc1 (dot256, 4 acc) then fc2 (dot160, 2 acc): row=tid&63, pt=tid>>6 ----
  {
    int r = tid & 63, pt = tid >> 6;
    const float* b1 = sb1 + pt*256;
    float aA = g_bfc1[r], aB = 0.f, aC = 0.f, aD = 0.f;
    const float4* w1 = (const float4*)(g_wfc1 + (size_t)r*256);
    #pragma unroll 8
    for (int c4=0; c4<64; c4+=4){
      aA += dot4(w1[c4],   b1 + c4*4);
      aB += dot4(w1[c4+1], b1 + c4*4 + 4);
      aC += dot4(w1[c4+2], b1 + c4*4 + 8);
      aD += dot4(w1[c4+3], b1 + c4*4 + 12);
    }
    sg[pt*128 + 64 + r] = lrelu((aA + aB) + (aC + aD));
    const float* b2 = sb2 + pt*160;
    float cA = g_bfc2[r], cB = 0.f;
    const float4* w2 = (const float4*)(g_wfc2 + (size_t)r*160);
    #pragma unroll 8
    for (int c4=0; c4<40; c4+=2){
      cA += dot4(w2[c4],   b2 + c4*4);
      cB += dot4(w2[c4+1], b2 + c4*4 + 4);
    }
    sg[pt*128 + r] = lrelu(cA + cB);
  }
  __syncthreads();
  // ---- out = wfc @ g + b (dot128, 2 acc): row=tid&63, pt=tid>>6 ----
  {
    int r = tid & 63, pt = tid >> 6, p = p0 + pt;
    const float* gg = sg + pt*128;
    float aA = g_bfc[r], aB = 0.f;
    const float4* w3 = (const float4*)(g_wfc + (size_t)r*128);
    #pragma unroll 8
    for (int c4=0; c4<32; c4+=2){
      aA += dot4(w3[c4],   gg + c4*4);
      aB += dot4(w3[c4+1], gg + c4*4 + 4);
    }
    float a = aA + aB;
    if (of32) ((float*)outv)[r*NN + p] = a;
    else      ((us*)outv)[r*NN + p] = f2b(a);
  }
}

extern "C" void kernel_launch(void* const* d_in, const int* in_sizes, int n_in,
                              void* d_out, int out_size, void* d_ws, size_t ws_size,
                              hipStream_t stream)
{
  (void)d_ws; (void)ws_size; (void)in_sizes; (void)n_in; (void)out_size;
  k0<<<64, 256, 0, stream>>>(
    d_in[0], d_in[1], d_in[2], d_in[3], d_in[4], d_in[5], d_in[6],
    d_in[7], d_in[8], d_in[9], d_in[10], d_in[11], d_in[12], d_in[13],
    d_in[14], d_in[15], d_in[16], d_in[17], d_in[18], d_in[19], d_in[20]);
  k1<<<375, 256, 0, stream>>>();
  k3<<<125, 256, 0, stream>>>(d_out);
}